// Round 9
// baseline (2115.615 us; speedup 1.0000x reference)
//
#include <hip/hip_runtime.h>

// Persistent-block VRNN, R8: 32 rows/block x 128 blocks (no cross-block sync).
// Halves chip-wide weight traffic (17GB -> 8.5GB/launch) since each weight
// byte feeds 2 row-tiles of MFMA. LLC-BW is the binding resource (R2 model).
// Weights: NORMAL loads (R7 showed nt on weights hurts). Streams (h_i, eps,
// outputs): non-temporal. Unified U layout (R6), sampling fused into P5.

typedef __attribute__((ext_vector_type(8))) short short8;
typedef __attribute__((ext_vector_type(4))) float f32x4;

#define Bt 4096
#define Td 16

// U layout (shorts): z@0, y_prev@64, h@320, s@832, y_cur@1344 ; stride 1608
#define US 1608
#define UZ 0
#define UY 64
#define UH 320
#define USs 832
#define UC 1344
#define TS 264
#define HZS 72

// weight ws offsets in short8 (16B) chunks (R2 layout)
#define OFF_WG   0          // gates dyn: K=832 ([z|y_prev|h]), N=2048, KT=26, NT=128
#define OFF_WPH  212992     // h_i gates: K=512, N=2048, KT=16, NT=128
#define OFF_W1   344064     // K=512 N=256 KT=16 NT=16
#define OFF_W2   360448     // K=256 N=256 KT=8
#define OFF_W3   368640
#define OFF_W4D  376832     // K=1024 ([s|y_cur|y_prev]) N=64 KT=32 NT=4
#define OFF_W4H  385024     // K=512 N=64 KT=16
#define OFF_W7D  389120     // K=768 ([s|y_prev]) N=64 KT=24
#define OFF_W7H  395264
#define OFF_W5   399360     // K=64 N=64 KT=2
#define OFF_W6   399872
#define OFF_W8   400384
#define OFF_W9   400896

#define O1 16777216
#define O2 20971520
#define O3 25165824

__device__ inline short f2bf(float f) {
  unsigned u = __builtin_bit_cast(unsigned, f);
  unsigned r = (u + 0x7FFFu + ((u >> 16) & 1u)) >> 16;
  return (short)(unsigned short)r;
}
__device__ inline float sigm(float x) { return 1.f / (1.f + __expf(-x)); }
__device__ inline float tanhx(float x) { return 1.f - 2.f / (__expf(2.f * x) + 1.f); }
__device__ inline unsigned pack2(float a, float b) {
  return (unsigned)(unsigned short)f2bf(a) | ((unsigned)(unsigned short)f2bf(b) << 16);
}
__device__ inline f32x4 unpack4(unsigned u0, unsigned u1) {
  f32x4 r;
  r[0] = __builtin_bit_cast(float, u0 << 16);
  r[1] = __builtin_bit_cast(float, u0 & 0xffff0000u);
  r[2] = __builtin_bit_cast(float, u1 << 16);
  r[3] = __builtin_bit_cast(float, u1 & 0xffff0000u);
  return r;
}

#define MFMA(a, b, c) __builtin_amdgcn_mfma_f32_16x16x32_bf16((a), (b), (c), 0, 0, 0)

// f32 row-major [K][N] (up to 3 concatenated row-ranges) -> bf16 MFMA frag
__global__ void conv_frag(const float* s0, int k0, const float* s1, int k1,
                          const float* s2, int k2, int N, short8* dst, int KT,
                          int total) {
  int idx = blockIdx.x * blockDim.x + threadIdx.x;
  if (idx >= total) return;
  int lane = idx & 63;
  int tt = idx >> 6;
  int kt = tt % KT;
  int nt = tt / KT;
  int c = nt * 16 + (lane & 15);
  int kb = kt * 32 + (lane >> 4) * 8;
  short8 v;
#pragma unroll
  for (int j = 0; j < 8; ++j) {
    int kc = kb + j;
    float f;
    if (kc < k0) f = s0[(size_t)kc * N + c];
    else if (kc < k0 + k1) f = s1[(size_t)(kc - k0) * N + c];
    else f = s2[(size_t)(kc - k0 - k1) * N + c];
    v[j] = f2bf(f);
  }
  dst[idx] = v;
}

struct Params {
  const float* h_i; const float* eps_inf; const float* eps_pri;
  const float* b_lstm;
  const float *b1, *b2, *b3, *b4, *b5, *b6, *b7, *b8, *b9;
  const short8 *WG, *WPH, *W1f, *W2f, *W3f, *W4D, *W4H, *W7D, *W7H,
               *W5f, *W6f, *W8f, *W9f;
  float* out;
};

__global__ __launch_bounds__(1024, 1) void vrnn_kernel(Params p) {
  __shared__ short U[32 * US];
  __shared__ short T1[32 * TS];
  __shared__ short T2[32 * TS];

  const int tid = threadIdx.x;
  const int wv = tid >> 6;
  const int lane = tid & 63;
  const int lrow = lane >> 4;
  const int lcol = lane & 15;
  const int rowbase = blockIdx.x * 32;
  // P4/P5 wave mapping
  const int net = wv >> 3;          // 0=inference, 1=prior
  const int rt4 = (wv >> 2) & 1;    // row tile for P4/P5
  const int q = wv & 3;             // N tile (Z=64 -> 4 tiles)

  // ---- stage h_i into U.h (NT stream) ----
  for (int i = tid; i < 32 * 512; i += 1024) {
    int r = i >> 9, c = i & 511;
    U[r * US + UH + c] =
        f2bf(__builtin_nontemporal_load(&p.h_i[(size_t)(rowbase + r) * 512 + c]));
  }
  __syncthreads();

  // ---- base = h_i @ WxH + b_lstm (2 row-tiles x 4 gates x 2 j, packed) ----
  unsigned base_pk[2][4][2][2];
  {
    f32x4 a2[2][4][2];
#pragma unroll
    for (int G = 0; G < 4; ++G)
#pragma unroll
      for (int j = 0; j < 2; ++j) {
        float b = p.b_lstm[G * 512 + wv * 32 + j * 16 + lcol];
        a2[0][G][j] = (f32x4){b, b, b, b};
        a2[1][G][j] = (f32x4){b, b, b, b};
      }
    for (int kt = 0; kt < 16; ++kt) {
      short8 a0 = *(const short8*)&U[lcol * US + UH + kt * 32 + lrow * 8];
      short8 a1 = *(const short8*)&U[(16 + lcol) * US + UH + kt * 32 + lrow * 8];
#pragma unroll
      for (int G = 0; G < 4; ++G)
#pragma unroll
        for (int j = 0; j < 2; ++j) {
          int nt = G * 32 + wv * 2 + j;
          short8 w = p.WPH[(size_t)(nt * 16 + kt) * 64 + lane];
          a2[0][G][j] = MFMA(a0, w, a2[0][G][j]);
          a2[1][G][j] = MFMA(a1, w, a2[1][G][j]);
        }
    }
#pragma unroll
    for (int rh = 0; rh < 2; ++rh)
#pragma unroll
      for (int G = 0; G < 4; ++G)
#pragma unroll
        for (int j = 0; j < 2; ++j) {
          base_pk[rh][G][j][0] = pack2(a2[rh][G][j][0], a2[rh][G][j][1]);
          base_pk[rh][G][j][1] = pack2(a2[rh][G][j][2], a2[rh][G][j][3]);
        }
  }
  // ---- base47: per wave (net, rt4, q), rows rt4*16.. ----
  f32x4 base47;
  {
    const short8* W = net ? p.W7H : p.W4H;
    const float* bb = net ? p.b7 : p.b4;
    float b = bb[q * 16 + lcol];
    base47 = (f32x4){b, b, b, b};
    for (int kt = 0; kt < 16; ++kt) {
      short8 a = *(const short8*)&U[(rt4 * 16 + lcol) * US + UH + kt * 32 + lrow * 8];
      short8 w = W[(q * 16 + kt) * 64 + lane];
      base47 = MFMA(a, w, base47);
    }
  }
  __syncthreads();
  // zero dynamic U region (cols 0..1600, all 32 rows)
  for (int i = tid; i < 6400; i += 1024) {
    int r = i / 200, c8 = i % 200;
    *(short8*)&U[r * US + c8 * 8] = (short8){0, 0, 0, 0, 0, 0, 0, 0};
  }
  f32x4 cst[2][2];
#pragma unroll
  for (int rh = 0; rh < 2; ++rh)
#pragma unroll
    for (int j = 0; j < 2; ++j) cst[rh][j] = (f32x4){0.f, 0.f, 0.f, 0.f};
  __syncthreads();

  // ---- time loop ----
  for (int t = 0; t < Td; ++t) {
    // P1: gates = [z|y_prev|h] @ WG + base  (full N, 2 row-tiles)
    f32x4 acc[2][4][2];
#pragma unroll
    for (int rh = 0; rh < 2; ++rh)
#pragma unroll
      for (int G = 0; G < 4; ++G)
#pragma unroll
        for (int j = 0; j < 2; ++j)
          acc[rh][G][j] = unpack4(base_pk[rh][G][j][0], base_pk[rh][G][j][1]);
    for (int kt = 0; kt < 26; ++kt) {
      short8 a0 = *(const short8*)&U[lcol * US + kt * 32 + lrow * 8];
      short8 a1 = *(const short8*)&U[(16 + lcol) * US + kt * 32 + lrow * 8];
#pragma unroll
      for (int G = 0; G < 4; ++G)
#pragma unroll
        for (int j = 0; j < 2; ++j) {
          int nt = G * 32 + wv * 2 + j;
          short8 w = p.WG[(size_t)(nt * 26 + kt) * 64 + lane];
          acc[0][G][j] = MFMA(a0, w, acc[0][G][j]);
          acc[1][G][j] = MFMA(a1, w, acc[1][G][j]);
        }
    }
    __syncthreads();

    // P2: LSTM pointwise; h_new -> U.h, c_new -> U.s
#pragma unroll
    for (int rh = 0; rh < 2; ++rh)
#pragma unroll
      for (int j = 0; j < 2; ++j)
#pragma unroll
        for (int r = 0; r < 4; ++r) {
          float iv = sigm(acc[rh][0][j][r]);
          float fv = sigm(acc[rh][1][j][r]);
          float gv = tanhx(acc[rh][2][j][r]);
          float ov = sigm(acc[rh][3][j][r]);
          float cn = fv * cst[rh][j][r] + iv * gv;
          cst[rh][j][r] = cn;
          float hn = ov * tanhx(cn);
          int row = rh * 16 + lrow * 4 + r;
          int col = wv * 32 + j * 16 + lcol;
          U[row * US + UH + col] = f2bf(hn);
          U[row * US + USs + col] = f2bf(cn);
        }
    __syncthreads();

    // P3: y-MLP, 32 rows, 1 N-tile/wave/layer, weights reused across row-tiles
    {
      float b = p.b1[wv * 16 + lcol];
      f32x4 o0 = (f32x4){b, b, b, b}, o1 = o0;
      for (int kt = 0; kt < 16; ++kt) {
        short8 a0 = *(const short8*)&U[lcol * US + UH + kt * 32 + lrow * 8];
        short8 a1 = *(const short8*)&U[(16 + lcol) * US + UH + kt * 32 + lrow * 8];
        short8 w = p.W1f[(wv * 16 + kt) * 64 + lane];
        o0 = MFMA(a0, w, o0);
        o1 = MFMA(a1, w, o1);
      }
#pragma unroll
      for (int r = 0; r < 4; ++r) {
        T1[(lrow * 4 + r) * TS + wv * 16 + lcol] = f2bf(fmaxf(o0[r], 0.f));
        T1[(16 + lrow * 4 + r) * TS + wv * 16 + lcol] = f2bf(fmaxf(o1[r], 0.f));
      }
    }
    __syncthreads();
    {
      float b = p.b2[wv * 16 + lcol];
      f32x4 o0 = (f32x4){b, b, b, b}, o1 = o0;
      for (int kt = 0; kt < 8; ++kt) {
        short8 a0 = *(const short8*)&T1[lcol * TS + kt * 32 + lrow * 8];
        short8 a1 = *(const short8*)&T1[(16 + lcol) * TS + kt * 32 + lrow * 8];
        short8 w = p.W2f[(wv * 8 + kt) * 64 + lane];
        o0 = MFMA(a0, w, o0);
        o1 = MFMA(a1, w, o1);
      }
#pragma unroll
      for (int r = 0; r < 4; ++r) {
        T2[(lrow * 4 + r) * TS + wv * 16 + lcol] = f2bf(fmaxf(o0[r], 0.f));
        T2[(16 + lrow * 4 + r) * TS + wv * 16 + lcol] = f2bf(fmaxf(o1[r], 0.f));
      }
    }
    __syncthreads();
    {
      float b = p.b3[wv * 16 + lcol];
      f32x4 o0 = (f32x4){b, b, b, b}, o1 = o0;
      for (int kt = 0; kt < 8; ++kt) {
        short8 a0 = *(const short8*)&T2[lcol * TS + kt * 32 + lrow * 8];
        short8 a1 = *(const short8*)&T2[(16 + lcol) * TS + kt * 32 + lrow * 8];
        short8 w = p.W3f[(wv * 8 + kt) * 64 + lane];
        o0 = MFMA(a0, w, o0);
        o1 = MFMA(a1, w, o1);
      }
#pragma unroll
      for (int r = 0; r < 4; ++r) {
        int crow = lrow * 4 + r;
        float v0 = fmaxf(o0[r], 0.f), v1 = fmaxf(o1[r], 0.f);
        U[crow * US + UC + wv * 16 + lcol] = f2bf(v0);
        U[(16 + crow) * US + UC + wv * 16 + lcol] = f2bf(v1);
        __builtin_nontemporal_store(
            v0, &p.out[(size_t)(rowbase + crow) * 4096 + t * 256 + wv * 16 + lcol]);
        __builtin_nontemporal_store(
            v1, &p.out[(size_t)(rowbase + 16 + crow) * 4096 + t * 256 + wv * 16 + lcol]);
      }
    }
    __syncthreads();

    // P4: h_z — wave (net, rt4, q), rows rt4*16..+16
    {
      f32x4 hz = base47;
      const int arow = rt4 * 16 + lcol;
      if (net == 0) {
        for (int kt = 0; kt < 32; ++kt) {
          int kk = kt < 16 ? USs + 32 * kt : (kt < 24 ? UC + 32 * (kt - 16) : UY + 32 * (kt - 24));
          short8 a = *(const short8*)&U[arow * US + kk + lrow * 8];
          hz = MFMA(a, p.W4D[(q * 32 + kt) * 64 + lane], hz);
        }
#pragma unroll
        for (int r = 0; r < 4; ++r)
          T1[(rt4 * 16 + lrow * 4 + r) * HZS + q * 16 + lcol] = f2bf(fmaxf(hz[r], 0.f));
      } else {
        for (int kt = 0; kt < 24; ++kt) {
          int kk = kt < 16 ? USs + 32 * kt : UY + 32 * (kt - 16);
          short8 a = *(const short8*)&U[arow * US + kk + lrow * 8];
          hz = MFMA(a, p.W7D[(q * 24 + kt) * 64 + lane], hz);
        }
#pragma unroll
        for (int r = 0; r < 4; ++r)
          T2[(rt4 * 16 + lrow * 4 + r) * HZS + q * 16 + lcol] = f2bf(fmaxf(hz[r], 0.f));
      }
    }
    __syncthreads();

    // P5: heads + sampling — wave (net, rt4, q)
    {
      const short8* Wm = net ? p.W8f : p.W5f;
      const short8* Wl = net ? p.W9f : p.W6f;
      const float* bm = net ? p.b8 : p.b5;
      const float* bl = net ? p.b9 : p.b6;
      const short* HZ = net ? T2 : T1;
      float b0 = bm[q * 16 + lcol], b1v = bl[q * 16 + lcol];
      f32x4 om = (f32x4){b0, b0, b0, b0};
      f32x4 ol = (f32x4){b1v, b1v, b1v, b1v};
#pragma unroll
      for (int kt = 0; kt < 2; ++kt) {
        short8 a = *(const short8*)&HZ[(rt4 * 16 + lcol) * HZS + kt * 32 + lrow * 8];
        om = MFMA(a, Wm[(q * 2 + kt) * 64 + lane], om);
        ol = MFMA(a, Wl[(q * 2 + kt) * 64 + lane], ol);
      }
      const float* eps = net ? p.eps_pri : p.eps_inf;
#pragma unroll
      for (int r = 0; r < 4; ++r) {
        int crow = rt4 * 16 + lrow * 4 + r;
        int grow = rowbase + crow;
        int col = q * 16 + lcol;
        float mv = fmaxf(om[r], 0.f), lv = fmaxf(ol[r], 0.f);
        float ev = __builtin_nontemporal_load(&eps[((size_t)t * Bt + grow) * 64 + col]);
        float zv = mv + ev * sqrtf(__expf(lv));
        if (net == 0) {
          size_t gb = (size_t)grow * 1024 + t * 64 + col;
          __builtin_nontemporal_store(mv, &p.out[O1 + gb]);
          __builtin_nontemporal_store(lv, &p.out[O2 + gb]);
          __builtin_nontemporal_store(zv, &p.out[O3 + ((size_t)(t * 2 + 0) * Bt + grow) * 64 + col]);
          U[crow * US + UZ + col] = f2bf(zv);
        } else {
          __builtin_nontemporal_store(zv, &p.out[O3 + ((size_t)(t * 2 + 1) * Bt + grow) * 64 + col]);
        }
      }
    }
    __syncthreads();

    // P6: y_cur -> y_prev (all 32 rows, local)
    {
      int row = tid >> 5, c8 = tid & 31;
      short8 v = *(const short8*)&U[row * US + UC + c8 * 8];
      *(short8*)&U[row * US + UY + c8 * 8] = v;
    }
    __syncthreads();
  }
}

extern "C" void kernel_launch(void* const* d_in, const int* in_sizes, int n_in,
                              void* d_out, int out_size, void* d_ws, size_t ws_size,
                              hipStream_t stream) {
  const float* h_i     = (const float*)d_in[0];
  const float* eps_inf = (const float*)d_in[1];
  const float* eps_pri = (const float*)d_in[2];
  const float* Wx      = (const float*)d_in[3];
  const float* Wh      = (const float*)d_in[4];
  const float* b_lstm  = (const float*)d_in[5];
  const float* W1 = (const float*)d_in[6];  const float* b1 = (const float*)d_in[7];
  const float* W2 = (const float*)d_in[8];  const float* b2 = (const float*)d_in[9];
  const float* W3 = (const float*)d_in[10]; const float* b3 = (const float*)d_in[11];
  const float* W4 = (const float*)d_in[12]; const float* b4 = (const float*)d_in[13];
  const float* W5 = (const float*)d_in[14]; const float* b5 = (const float*)d_in[15];
  const float* W6 = (const float*)d_in[16]; const float* b6 = (const float*)d_in[17];
  const float* W7 = (const float*)d_in[18]; const float* b7 = (const float*)d_in[19];
  const float* W8 = (const float*)d_in[20]; const float* b8 = (const float*)d_in[21];
  const float* W9 = (const float*)d_in[22]; const float* b9 = (const float*)d_in[23];
  short8* ws = (short8*)d_ws;
  const float* nil = nullptr;

  auto cv = [&](const float* s0, int k0, const float* s1, int k1,
                const float* s2, int k2, int N, int off, int KT, int NT) {
    int total = NT * KT * 64;
    conv_frag<<<(total + 255) / 256, 256, 0, stream>>>(s0, k0, s1, k1, s2, k2,
                                                       N, ws + off, KT, total);
  };
  // gates dyn: [z (Wx rows 0:64) | y_prev (Wx rows 576:832) | h (Wh)]
  cv(Wx, 64, Wx + 576 * 2048, 256, Wh, 512, 2048, OFF_WG, 26, 128);
  cv(Wx + 64 * 2048, 512, nil, 0, nil, 0, 2048, OFF_WPH, 16, 128);
  cv(W1, 512, nil, 0, nil, 0, 256, OFF_W1, 16, 16);
  cv(W2, 256, nil, 0, nil, 0, 256, OFF_W2, 8, 16);
  cv(W3, 256, nil, 0, nil, 0, 256, OFF_W3, 8, 16);
  // W4 dyn: K-order [s | y_cur | y_prev] to match P4's kk mapping
  cv(W4 + 512 * 64, 512, W4 + 1024 * 64, 256, W4 + 1280 * 64, 256, 64, OFF_W4D, 32, 4);
  cv(W4, 512, nil, 0, nil, 0, 64, OFF_W4H, 16, 4);
  // W7 dyn: [s | y_prev]
  cv(W7 + 512 * 64, 512, W7 + 1024 * 64, 256, nil, 0, 64, OFF_W7D, 24, 4);
  cv(W7, 512, nil, 0, nil, 0, 64, OFF_W7H, 16, 4);
  cv(W5, 64, nil, 0, nil, 0, 64, OFF_W5, 2, 4);
  cv(W6, 64, nil, 0, nil, 0, 64, OFF_W6, 2, 4);
  cv(W8, 64, nil, 0, nil, 0, 64, OFF_W8, 2, 4);
  cv(W9, 64, nil, 0, nil, 0, 64, OFF_W9, 2, 4);

  Params P{h_i, eps_inf, eps_pri, b_lstm,
           b1, b2, b3, b4, b5, b6, b7, b8, b9,
           ws + OFF_WG, ws + OFF_WPH, ws + OFF_W1, ws + OFF_W2, ws + OFF_W3,
           ws + OFF_W4D, ws + OFF_W4H, ws + OFF_W7D, ws + OFF_W7H,
           ws + OFF_W5, ws + OFF_W6, ws + OFF_W8, ws + OFF_W9,
           (float*)d_out};
  vrnn_kernel<<<128, 1024, 0, stream>>>(P);
}